// Round 6
// baseline (687.599 us; speedup 1.0000x reference)
//
#include <hip/hip_runtime.h>

#define B_   8
#define C_   512
#define H_   96
#define W_   96
#define HW_  (H_*W_)
#define NPIX_ (B_*HW_)
#define TMPO_ELEMS 9437184   // one bf16 tile slot: B*W*H*128

typedef unsigned short u16;
typedef __attribute__((ext_vector_type(8))) short short8;   // 8 bf16 = 4 VGPRs (MFMA A/B frag)
typedef __attribute__((ext_vector_type(4))) float f32x4;    // MFMA C/D frag
typedef __attribute__((address_space(1))) void as1_void;
typedef __attribute__((address_space(3))) void as3_void;

__device__ __forceinline__ float bf2f(u16 u) {
  unsigned int x = ((unsigned int)u) << 16;
  return __uint_as_float(x);
}
__device__ __forceinline__ u16 f2bf(float f) {
  unsigned int x = __float_as_uint(f);
  x += 0x7fffu + ((x >> 16) & 1u);   // RNE
  return (u16)(x >> 16);
}

// async global->LDS, 16 B per lane; LDS dest = wave-uniform base + lane*16
__device__ __forceinline__ void gld16(const void* g, void* l) {
  __builtin_amdgcn_global_load_lds((as1_void*)(const_cast<void*>(g)),
                                   (as3_void*)(l), 16, 0, 0);
}

// raw barrier with compiler memory fences (no vmcnt/lgkm drain)
__device__ __forceinline__ void barrier_raw() {
  asm volatile("" ::: "memory");
  __builtin_amdgcn_s_barrier();
  asm volatile("" ::: "memory");
}

// ---------------- prepass: x [b][c][hw] fp32 -> xT [b][pix][512] bf16
__global__ __launch_bounds__(256) void transpose_kernel(
    const float* __restrict__ x, u16* __restrict__ xT)
{
  const int p0 = blockIdx.x * 64, c0 = blockIdx.y * 64, b = blockIdx.z;
  __shared__ float tile[64*65];
  const int t = threadIdx.x;
  {
    const int cc = t >> 2, ps = (t & 3) * 16;
    const float* src = x + ((size_t)b*C_ + c0 + cc)*HW_ + p0 + ps;
    float4 f0 = *(const float4*)(src);
    float4 f1 = *(const float4*)(src + 4);
    float4 f2 = *(const float4*)(src + 8);
    float4 f3 = *(const float4*)(src + 12);
    float* d = tile + cc*65 + ps;
    d[0]=f0.x; d[1]=f0.y; d[2]=f0.z;  d[3]=f0.w;
    d[4]=f1.x; d[5]=f1.y; d[6]=f1.z;  d[7]=f1.w;
    d[8]=f2.x; d[9]=f2.y; d[10]=f2.z; d[11]=f2.w;
    d[12]=f3.x; d[13]=f3.y; d[14]=f3.z; d[15]=f3.w;
  }
  __syncthreads();
#pragma unroll
  for (int pass = 0; pass < 2; ++pass) {
    const int pr = pass*32 + (t >> 3), cs = (t & 7) * 8;
    union { u16 s[8]; uint4 v; } tmp;
#pragma unroll
    for (int i = 0; i < 8; ++i) tmp.s[i] = f2bf(tile[(cs + i)*65 + pr]);
    *(uint4*)(xT + ((size_t)b*HW_ + p0 + pr)*C_ + c0 + cs) = tmp.v;
  }
}

// ---------------- prepass: weights fp32 -> bf16 parked in d_out (dead until outW).
__global__ __launch_bounds__(256) void wconv_kernel(
    const float* __restrict__ Wq, const float* __restrict__ Wk,
    const float* __restrict__ Wv, u16* __restrict__ wdst)
{
  const int i = (blockIdx.x * 256 + threadIdx.x) * 4;
  const float* src; int off;
  if (i < 32768)      { src = Wq; off = 0; }
  else if (i < 65536) { src = Wk; off = 32768; }
  else                { src = Wv; off = 65536; }
  float4 f = *(const float4*)(src + (i - off));
  union { u16 s[4]; uint2 v; } o;
  o.s[0] = f2bf(f.x); o.s[1] = f2bf(f.y); o.s[2] = f2bf(f.z); o.s[3] = f2bf(f.w);
  *(uint2*)(wdst + i) = o.v;
}

// ---------------- fused MFMA projection GEMM (q,k,v in one launch):
// grid (72, 5, 8). y=0 -> qk[b][pix][128]; y=1..4 -> vp[b][pix][512] tile (y-1)*128.
// 2-phase double-buffered staging: one raw barrier + vmcnt(0) per K-step;
// prefetch of step k+1 issued after the barrier, hidden under ds_read+MFMA.
__global__ __launch_bounds__(256) void mfma_proj(
    const u16* __restrict__ xT, const u16* __restrict__ Wt,
    const float* __restrict__ bq, const float* __restrict__ bk,
    const float* __restrict__ bv, u16* __restrict__ qkp, u16* __restrict__ vpp)
{
  __shared__ __align__(16) u16 As[2*128*32];   // double-buffered [pix][32k]
  __shared__ __align__(16) u16 Bs[2*128*32];   // double-buffered [ch][32k]
  const int b  = blockIdx.z;
  const int p0 = blockIdx.x * 128;
  const int n0 = blockIdx.y * 128;           // global weight row base (0..512)
  const int t = threadIdx.x;
  const int wv = t >> 6, lane = t & 63;
  const int wr = wv >> 1, wc = wv & 1;       // wave's 64x64 quadrant
  const int lhi = lane >> 4, llo = lane & 15;

  // staging: lane covers row = chunk*16 + (lane>>2), k-quad = (lane&3)^(row&3)
  const int srow = lane >> 2;
  const int skq  = (lane & 3) ^ (srow & 3);
  const u16* aG = xT + ((size_t)b*HW_ + p0 + srow) * C_ + skq * 8;
  const u16* bG = Wt + ((size_t)(n0 + srow)) * C_ + skq * 8;

  // frag read offsets (elems): quad q of row R sits at position q^(R&3)
  const int swz = (lhi ^ (llo & 3)) * 8;
  int aOff[4], bOff[4];
#pragma unroll
  for (int i = 0; i < 4; ++i) aOff[i] = (wr*64 + i*16 + llo)*32 + swz;
#pragma unroll
  for (int j = 0; j < 4; ++j) bOff[j] = (wc*64 + j*16 + llo)*32 + swz;

  auto stage = [&](int bi, int k0) {
#pragma unroll
    for (int i = 0; i < 2; ++i) {
      const int chunk = wv*2 + i;            // wave-uniform
      gld16(aG + (size_t)chunk*16*C_ + k0, (void*)(As + bi*4096 + chunk*512));
      gld16(bG + (size_t)chunk*16*C_ + k0, (void*)(Bs + bi*4096 + chunk*512));
    }
  };

  f32x4 acc[4][4];
#pragma unroll
  for (int i = 0; i < 4; ++i)
#pragma unroll
    for (int j = 0; j < 4; ++j) acc[i][j] = (f32x4){0.f, 0.f, 0.f, 0.f};

  stage(0, 0);
  for (int ki = 0; ki < 16; ++ki) {
    const int cur = ki & 1;
    // my buffer-cur loads (issued last iter) had the whole previous compute
    // phase in flight; counted drain here, then sync all waves.
    asm volatile("s_waitcnt vmcnt(0)" ::: "memory");
    __builtin_amdgcn_s_barrier();
    asm volatile("" ::: "memory");
    if (ki < 15) stage(cur ^ 1, (ki + 1) * 32);   // in flight across compute
    const u16* Ab = As + cur*4096;
    const u16* Bb = Bs + cur*4096;
    short8 af[4], bfr[4];
#pragma unroll
    for (int i = 0; i < 4; ++i) af[i]  = *(const short8*)(Ab + aOff[i]);
#pragma unroll
    for (int j = 0; j < 4; ++j) bfr[j] = *(const short8*)(Bb + bOff[j]);
#pragma unroll
    for (int i = 0; i < 4; ++i)
#pragma unroll
      for (int j = 0; j < 4; ++j)
        acc[i][j] = __builtin_amdgcn_mfma_f32_16x16x32_bf16(af[i], bfr[j], acc[i][j], 0, 0, 0);
  }

  // epilogue: D row (pix) = quad*4+reg, col = lane&15; route by blockIdx.y
  const bool isQK = (blockIdx.y == 0);
  u16* op = isQK ? qkp : vpp;
  const int NCH = isQK ? 128 : 512;
  const int chBase = isQK ? 0 : (n0 - 128);
#pragma unroll
  for (int j = 0; j < 4; ++j) {
    const int chl = wc*64 + j*16 + llo;      // 0..127 within tile
    const float bias = isQK ? ((chl < 64) ? bq[chl] : bk[chl - 64])
                            : bv[chBase + chl];
#pragma unroll
    for (int i = 0; i < 4; ++i) {
      const int pr = p0 + wr*64 + i*16 + lhi*4;
      u16* dst = op + ((size_t)b*HW_ + pr) * NCH + chBase + chl;
#pragma unroll
      for (int r = 0; r < 4; ++r)
        dst[(size_t)r * NCH] = f2bf(acc[i][j][r] + bias);
    }
  }
}

// ---------------- eH logits: block per (w, b). qk bf16 [pix][128]: q=ch 0..63, k=ch 64..127
// writes raw fp32 logits attL[b][h][w][96] (diag = -inf)
__global__ __launch_bounds__(256) void score_col_kernel(
    const u16* __restrict__ qk, float* __restrict__ attL)
{
  const int w = blockIdx.x, b = blockIdx.y;
  __shared__ float qs[96*68];
  __shared__ float ks[96*68];
  const int t = threadIdx.x;
  for (int r = 0; r < 6; ++r) {
    int f = r*256 + t;                   // 1536 uint4 chunks
    int p = f >> 4, c8 = (f & 15) * 8;
    uint4 u = *(const uint4*)(qk + ((size_t)(b*HW_ + p*W_ + w))*128 + c8);
    float d[8];
    d[0]=bf2f(u.x & 0xffff); d[1]=bf2f(u.x >> 16);
    d[2]=bf2f(u.y & 0xffff); d[3]=bf2f(u.y >> 16);
    d[4]=bf2f(u.z & 0xffff); d[5]=bf2f(u.z >> 16);
    d[6]=bf2f(u.w & 0xffff); d[7]=bf2f(u.w >> 16);
    float* dst = (c8 < 64) ? (qs + p*68 + c8) : (ks + p*68 + (c8 - 64));
    *(float4*)(dst)     = make_float4(d[0], d[1], d[2], d[3]);
    *(float4*)(dst + 4) = make_float4(d[4], d[5], d[6], d[7]);
  }
  __syncthreads();
  const int ty = t >> 4, tx = t & 15;
  float e[6][6] = {};
#pragma unroll 8
  for (int c = 0; c < 64; ++c) {
    float qv[6], kv[6];
#pragma unroll
    for (int a = 0; a < 6; ++a) qv[a] = qs[(ty*6+a)*68 + c];
#pragma unroll
    for (int bb = 0; bb < 6; ++bb) kv[bb] = ks[(tx*6+bb)*68 + c];
#pragma unroll
    for (int a = 0; a < 6; ++a)
#pragma unroll
      for (int bb = 0; bb < 6; ++bb)
        e[a][bb] = fmaf(qv[a], kv[bb], e[a][bb]);
  }
#pragma unroll
  for (int a = 0; a < 6; ++a) {
    int h = ty*6 + a;
    size_t base = ((size_t)((b*H_ + h)*W_ + w)) * 96;
#pragma unroll
    for (int bb = 0; bb < 6; ++bb) {
      int p = tx*6 + bb;
      attL[base + p] = (h == p) ? -INFINITY : e[a][bb];
    }
  }
}

// ---------------- eW logits + fused softmax: block per (h, b).
__global__ __launch_bounds__(256) void score_row_kernel(
    const u16* __restrict__ qk, const float* __restrict__ attL,
    u16* __restrict__ attF)
{
  const int h = blockIdx.x, b = blockIdx.y;
  __shared__ float smem[2*96*68];            // qs|ks; reused as esW[96][97]
  float* qs = smem;
  float* ks = smem + 96*68;
  const int t = threadIdx.x;
  for (int r = 0; r < 6; ++r) {
    int f = r*256 + t;
    int p = f >> 4, c8 = (f & 15) * 8;
    uint4 u = *(const uint4*)(qk + ((size_t)(b*HW_ + h*W_ + p))*128 + c8);
    float d[8];
    d[0]=bf2f(u.x & 0xffff); d[1]=bf2f(u.x >> 16);
    d[2]=bf2f(u.y & 0xffff); d[3]=bf2f(u.y >> 16);
    d[4]=bf2f(u.z & 0xffff); d[5]=bf2f(u.z >> 16);
    d[6]=bf2f(u.w & 0xffff); d[7]=bf2f(u.w >> 16);
    float* dst = (c8 < 64) ? (qs + p*68 + c8) : (ks + p*68 + (c8 - 64));
    *(float4*)(dst)     = make_float4(d[0], d[1], d[2], d[3]);
    *(float4*)(dst + 4) = make_float4(d[4], d[5], d[6], d[7]);
  }
  __syncthreads();
  const int ty = t >> 4, tx = t & 15;
  float e[6][6] = {};
#pragma unroll 8
  for (int c = 0; c < 64; ++c) {
    float qv[6], kv[6];
#pragma unroll
    for (int a = 0; a < 6; ++a) qv[a] = qs[(ty*6+a)*68 + c];
#pragma unroll
    for (int bb = 0; bb < 6; ++bb) kv[bb] = ks[(tx*6+bb)*68 + c];
#pragma unroll
    for (int a = 0; a < 6; ++a)
#pragma unroll
      for (int bb = 0; bb < 6; ++bb)
        e[a][bb] = fmaf(qv[a], kv[bb], e[a][bb]);
  }
  __syncthreads();                           // all qs/ks reads done
  float* esW = smem;                         // [96][97]
#pragma unroll
  for (int a = 0; a < 6; ++a)
#pragma unroll
    for (int bb = 0; bb < 6; ++bb)
      esW[(ty*6 + a)*97 + tx*6 + bb] = e[a][bb];
  __syncthreads();
  // fused softmax: 2 lanes per pixel (lane pair via shfl_xor 1)
  if (t < 192) {
    const int w = t >> 1, hf = t & 1;
    float v[96];
    if (hf == 0) {
      const float4* src = (const float4*)(attL + ((size_t)((b*H_ + h)*W_ + w)) * 96);
#pragma unroll
      for (int i = 0; i < 24; ++i) {
        float4 f4 = src[i];
        v[4*i]=f4.x; v[4*i+1]=f4.y; v[4*i+2]=f4.z; v[4*i+3]=f4.w;
      }
    } else {
      const float* src = esW + w*97;
#pragma unroll
      for (int i = 0; i < 96; ++i) v[i] = src[i];
    }
    float m = v[0];
#pragma unroll
    for (int i = 1; i < 96; ++i) m = fmaxf(m, v[i]);
    m = fmaxf(m, __shfl_xor(m, 1, 64));
    float s = 0.f;
#pragma unroll
    for (int i = 0; i < 96; ++i) { v[i] = __expf(v[i] - m); s += v[i]; }
    s += __shfl_xor(s, 1, 64);
    const float inv = __frcp_rn(s);
    u16* dst = attF + ((size_t)((b*H_ + h)*W_ + w)) * 192 + hf*96;
#pragma unroll
    for (int i = 0; i < 12; ++i) {
      union { u16 s4[8]; uint4 u; } o;
#pragma unroll
      for (int k = 0; k < 8; ++k) o.s4[k] = f2bf(v[i*8 + k] * inv);
      ((uint4*)dst)[i] = o.u;
    }
  }
}

// ---------------- outH: block per (w, ytile, b); c0 = cr0 + y*128, tmpo slot = y.
// tmpo[slot][b][w][h][cl] (bf16) = sum_p attH[h,p]*v[c0+cl,p,w].
// 2-phase: v-tile i+1 prefetched into regs while computing tile i.
__global__ __launch_bounds__(256) void outH_kernel(
    const u16* __restrict__ attF, const u16* __restrict__ vp,
    int cr0, u16* __restrict__ tmpo)
{
  const int w = blockIdx.x, b = blockIdx.z;
  const int c0 = cr0 + (int)blockIdx.y * 128;
  u16* tdst = tmpo + (size_t)blockIdx.y * TMPO_ELEMS;
  __shared__ __align__(16) u16 as16[96*104];   // attH bf16 [h][p], pad 104
  __shared__ __align__(16) float vs[2][16*132];
  const int t = threadIdx.x;
  const int ty = t >> 4, tx = t & 15;
  // stage attH (raw bf16 copy)
  for (int r = 0; r < 5; ++r) {
    int f = r*256 + t;
    if (f < 1152) {
      int hh = f / 12, p8 = (f % 12) * 8;
      *(uint4*)(as16 + hh*104 + p8) =
          *(const uint4*)(attF + ((size_t)((b*H_ + hh)*W_ + w))*192 + p8);
    }
  }
  // thread stages row pp=ty, cols tx*8..+7; pixel = (p0+ty)*W + w
  const u16* vbase = vp + ((size_t)b*HW_ + (size_t)ty*W_ + w)*C_ + c0 + tx*8;
  uint4 rv = *(const uint4*)(vbase);           // tile 0
  {
    float* d = &vs[0][ty*132 + tx*8];
    d[0]=bf2f((u16)(rv.x&0xffff)); d[1]=bf2f((u16)(rv.x>>16));
    d[2]=bf2f((u16)(rv.y&0xffff)); d[3]=bf2f((u16)(rv.y>>16));
    d[4]=bf2f((u16)(rv.z&0xffff)); d[5]=bf2f((u16)(rv.z>>16));
    d[6]=bf2f((u16)(rv.w&0xffff)); d[7]=bf2f((u16)(rv.w>>16));
  }
  float acc[6][8] = {};
  for (int i = 0; i < 6; ++i) {
    const int p0 = i*16;
    uint4 rn;
    if (i < 5) rn = *(const uint4*)(vbase + (size_t)(p0+16)*W_*C_);  // prefetch
    asm volatile("s_waitcnt lgkmcnt(0)" ::: "memory");   // my LDS writes committed
    __builtin_amdgcn_s_barrier();
    asm volatile("" ::: "memory");
    const float* vb = vs[i&1];
#pragma unroll
    for (int pp = 0; pp < 16; ++pp) {
      float av[6];
#pragma unroll
      for (int a = 0; a < 6; ++a) av[a] = bf2f(as16[(ty + 16*a)*104 + p0 + pp]);
      float4 v0 = *(const float4*)(vb + pp*132 + tx*8);
      float4 v1 = *(const float4*)(vb + pp*132 + tx*8 + 4);
      float vv[8] = {v0.x,v0.y,v0.z,v0.w, v1.x,v1.y,v1.z,v1.w};
#pragma unroll
      for (int a = 0; a < 6; ++a)
#pragma unroll
        for (int j = 0; j < 8; ++j)
          acc[a][j] = fmaf(av[a], vv[j], acc[a][j]);
    }
    if (i < 5) {
      float* d = &vs[(i+1)&1][ty*132 + tx*8];
      d[0]=bf2f((u16)(rn.x&0xffff)); d[1]=bf2f((u16)(rn.x>>16));
      d[2]=bf2f((u16)(rn.y&0xffff)); d[3]=bf2f((u16)(rn.y>>16));
      d[4]=bf2f((u16)(rn.z&0xffff)); d[5]=bf2f((u16)(rn.z>>16));
      d[6]=bf2f((u16)(rn.w&0xffff)); d[7]=bf2f((u16)(rn.w>>16));
    }
  }
  // store bf16, lane owns c = tx*8..tx*8+7 (contiguous 16 B)
#pragma unroll
  for (int a = 0; a < 6; ++a) {
    int hh = ty + 16*a;
    union { u16 s4[8]; uint4 u; } o;
#pragma unroll
    for (int j = 0; j < 8; ++j) o.s4[j] = f2bf(acc[a][j]);
    *(uint4*)(tdst + (((size_t)b*W_ + w)*H_ + hh)*128 + tx*8) = o.u;
  }
}

// ---------------- outW + fuse outH tile + residual:
// out = gamma*(sum_p attW[w,p]*v[c,h,p] + tmpo) + x; same 2-phase structure,
// epilogue also double-buffered (tmpo chunk + x residual prefetch).
__global__ __launch_bounds__(256) void outW_kernel(
    const u16* __restrict__ attF, const u16* __restrict__ vp,
    const u16* __restrict__ tmpo, const float* __restrict__ x,
    const float* __restrict__ gammap, int cr0, float* __restrict__ out)
{
  const int h = blockIdx.x, b = blockIdx.z;
  const int c0 = cr0 + (int)blockIdx.y * 128;
  const u16* tsrc = tmpo + (size_t)blockIdx.y * TMPO_ELEMS;
  __shared__ __align__(16) u16 as16[96*104];   // attW [w][p]; reused as ts dbuf
  __shared__ __align__(16) float vs[2][16*132];
  const int t = threadIdx.x;
  const int ty = t >> 4, tx = t & 15;
  // stage attW (raw bf16 copy)
  for (int r = 0; r < 5; ++r) {
    int f = r*256 + t;
    if (f < 1152) {
      int wl = f / 12, p8 = (f % 12) * 8;
      *(uint4*)(as16 + wl*104 + p8) =
          *(const uint4*)(attF + ((size_t)((b*H_ + h)*W_ + wl))*192 + 96 + p8);
    }
  }
  // thread stages row pp=ty, cols tx*8..+7; pixel = h*W + (p0+ty)
  const u16* vbase = vp + ((size_t)b*HW_ + (size_t)h*W_ + ty)*C_ + c0 + tx*8;
  uint4 rv = *(const uint4*)(vbase);
  {
    float* d = &vs[0][ty*132 + tx*8];
    d[0]=bf2f((u16)(rv.x&0xffff)); d[1]=bf2f((u16)(rv.x>>16));
    d[2]=bf2f((u16)(rv.y&0xffff)); d[3]=bf2f((u16)(rv.y>>16));
    d[4]=bf2f((u16)(rv.z&0xffff)); d[5]=bf2f((u16)(rv.z>>16));
    d[6]=bf2f((u16)(rv.w&0xffff)); d[7]=bf2f((u16)(rv.w>>16));
  }
  float acc[8][6] = {};
  for (int i = 0; i < 6; ++i) {
    const int p0 = i*16;
    uint4 rn;
    if (i < 5) rn = *(const uint4*)(vbase + (size_t)(p0+16)*C_);   // prefetch
    asm volatile("s_waitcnt lgkmcnt(0)" ::: "memory");
    __builtin_amdgcn_s_barrier();
    asm volatile("" ::: "memory");
    const float* vb = vs[i&1];
#pragma unroll
    for (int pp = 0; pp < 16; ++pp) {
      float aw[6];
#pragma unroll
      for (int j = 0; j < 6; ++j) aw[j] = bf2f(as16[(tx + 16*j)*104 + p0 + pp]);
      float4 v0 = *(const float4*)(vb + pp*132 + ty*8);
      float4 v1 = *(const float4*)(vb + pp*132 + ty*8 + 4);
      float vv[8] = {v0.x,v0.y,v0.z,v0.w, v1.x,v1.y,v1.z,v1.w};
#pragma unroll
      for (int a = 0; a < 8; ++a)
#pragma unroll
        for (int j = 0; j < 6; ++j)
          acc[a][j] = fmaf(vv[a], aw[j], acc[a][j]);
    }
    if (i < 5) {
      float* d = &vs[(i+1)&1][ty*132 + tx*8];
      d[0]=bf2f((u16)(rn.x&0xffff)); d[1]=bf2f((u16)(rn.x>>16));
      d[2]=bf2f((u16)(rn.y&0xffff)); d[3]=bf2f((u16)(rn.y>>16));
      d[4]=bf2f((u16)(rn.z&0xffff)); d[5]=bf2f((u16)(rn.z>>16));
      d[6]=bf2f((u16)(rn.w&0xffff)); d[7]=bf2f((u16)(rn.w>>16));
    }
  }
  // epilogue: 6 chunks of 16 w; tmpo + x prefetched one chunk ahead.
  const float g = gammap[0];
  float* ts = (float*)as16;              // [2][16*132] fp32, 16.9 KB <= 19.97 KB
  uint4 rt = *(const uint4*)(tsrc + (((size_t)b*W_ + ty)*H_ + h)*128 + tx*8);
  float xr[8];
  {
    const size_t xb = ((size_t)(b*C_ + c0 + ty*8)*H_ + h)*W_ + tx;
#pragma unroll
    for (int a = 0; a < 8; ++a) xr[a] = x[xb + (size_t)a*HW_];
  }
  barrier_raw();                         // all waves done reading as16 (attW)
  {
    float* d = ts + ty*132 + tx*8;
    d[0]=bf2f((u16)(rt.x&0xffff)); d[1]=bf2f((u16)(rt.x>>16));
    d[2]=bf2f((u16)(rt.y&0xffff)); d[3]=bf2f((u16)(rt.y>>16));
    d[4]=bf2f((u16)(rt.z&0xffff)); d[5]=bf2f((u16)(rt.z>>16));
    d[6]=bf2f((u16)(rt.w&0xffff)); d[7]=bf2f((u16)(rt.w>>16));
  }
  for (int j = 0; j < 6; ++j) {
    uint4 rtn; float xrn[8];
    if (j < 5) {
      rtn = *(const uint4*)(tsrc + (((size_t)b*W_ + (j+1)*16 + ty)*H_ + h)*128 + tx*8);
      const size_t xb = ((size_t)(b*C_ + c0 + ty*8)*H_ + h)*W_ + tx + 16*(j+1);
#pragma unroll
      for (int a = 0; a < 8; ++a) xrn[a] = x[xb + (size_t)a*HW_];
    }
    asm volatile("s_waitcnt lgkmcnt(0)" ::: "memory");
    __builtin_amdgcn_s_barrier();
    asm volatile("" ::: "memory");
    const float* tb = ts + (j&1)*(16*132);
#pragma unroll
    for (int a = 0; a < 8; ++a) {
      size_t idx = ((size_t)(b*C_ + c0 + ty*8 + a)*H_ + h)*W_ + tx + 16*j;
      out[idx] = g*(acc[a][j] + tb[tx*132 + ty*8 + a]) + xr[a];
    }
    if (j < 5) {
      float* d = ts + ((j+1)&1)*(16*132) + ty*132 + tx*8;
      d[0]=bf2f((u16)(rtn.x&0xffff)); d[1]=bf2f((u16)(rtn.x>>16));
      d[2]=bf2f((u16)(rtn.y&0xffff)); d[3]=bf2f((u16)(rtn.y>>16));
      d[4]=bf2f((u16)(rtn.z&0xffff)); d[5]=bf2f((u16)(rtn.z>>16));
      d[6]=bf2f((u16)(rtn.w&0xffff)); d[7]=bf2f((u16)(rtn.w>>16));
#pragma unroll
      for (int a = 0; a < 8; ++a) xr[a] = xrn[a];
    }
  }
}

extern "C" void kernel_launch(void* const* d_in, const int* in_sizes, int n_in,
                              void* d_out, int out_size, void* d_ws, size_t ws_size,
                              hipStream_t stream) {
  const float* x     = (const float*)d_in[0];
  const float* Wq    = (const float*)d_in[1];
  const float* bq    = (const float*)d_in[2];
  const float* Wk    = (const float*)d_in[3];
  const float* bk    = (const float*)d_in[4];
  const float* Wv    = (const float*)d_in[5];
  const float* bv    = (const float*)d_in[6];
  const float* gamma = (const float*)d_in[7];
  float* out = (float*)d_out;
  char* ws = (char*)d_ws;

  // ws layout (169,869,312 B):
  //   xT    @0        : bf16 [B][HW][512] (75,497,472 B), live through mfma_proj
  //   attF  @0        : bf16 [B][H][W][192] (28,311,552 B)  — overlays dead xT
  //   attL  @28311552 : fp32 [B][H][W][96]  (28,311,552 B)  — overlays dead xT
  //   tmpo  @56623104 : bf16 2 slots x [B][W][H][128] (2 x 18,874,368 B)
  //   qk    @75497472 : bf16 [B][HW][128] (18,874,368 B)
  //   vp    @94371840 : bf16 [B][HW][512] (75,497,472 B)
  // weights: bf16 [640][512] (655,360 B) parked in d_out (dead until outW).
  u16*   xT   = (u16*)ws;
  u16*   attF = (u16*)ws;
  float* attL = (float*)(ws + 28311552);
  u16*   tmpo = (u16*)(ws + 56623104);
  u16*   qk   = (u16*)(ws + 75497472);
  u16*   vp   = (u16*)(ws + 94371840);
  u16*   wbf  = (u16*)d_out;

  dim3 blk(256);
  wconv_kernel<<<320, blk, 0, stream>>>(Wq, Wk, Wv, wbf);
  transpose_kernel<<<dim3(HW_/64, C_/64, B_), blk, 0, stream>>>(x, xT);
  mfma_proj<<<dim3(HW_/128, 5, B_), blk, 0, stream>>>(xT, wbf, bq, bk, bv, qk, vp);
  score_col_kernel<<<dim3(W_, B_), blk, 0, stream>>>(qk, attL);
  score_row_kernel<<<dim3(H_, B_), blk, 0, stream>>>(qk, attL, attF);
  for (int r = 0; r < 2; ++r) {
    outH_kernel<<<dim3(W_, 2, B_), blk, 0, stream>>>(attF, vp, r*256, tmpo);
    outW_kernel<<<dim3(H_, 2, B_), blk, 0, stream>>>(attF, vp, tmpo, x, gamma, r*256, out);
  }
}

// Round 7
// 514.073 us; speedup vs baseline: 1.3376x; 1.3376x over previous
//
#include <hip/hip_runtime.h>

#define B_   8
#define C_   512
#define H_   96
#define W_   96
#define HW_  (H_*W_)
#define NPIX_ (B_*HW_)
#define TMPO_ELEMS 9437184   // one bf16 tile slot: B*W*H*128

typedef unsigned short u16;
typedef __attribute__((ext_vector_type(8))) short short8;   // 8 bf16 = 4 VGPRs (MFMA A/B frag)
typedef __attribute__((ext_vector_type(4))) float f32x4;    // MFMA C/D frag
typedef __attribute__((address_space(1))) void as1_void;
typedef __attribute__((address_space(3))) void as3_void;

__device__ __forceinline__ float bf2f(u16 u) {
  unsigned int x = ((unsigned int)u) << 16;
  return __uint_as_float(x);
}
__device__ __forceinline__ u16 f2bf(float f) {
  unsigned int x = __float_as_uint(f);
  x += 0x7fffu + ((x >> 16) & 1u);   // RNE
  return (u16)(x >> 16);
}

// async global->LDS, 16 B per lane; LDS dest = wave-uniform base + lane*16
__device__ __forceinline__ void gld16(const void* g, void* l) {
  __builtin_amdgcn_global_load_lds((as1_void*)(const_cast<void*>(g)),
                                   (as3_void*)(l), 16, 0, 0);
}

// ---------------- prepass: x [b][c][hw] fp32 -> xT [b][pix][512] bf16
__global__ __launch_bounds__(256) void transpose_kernel(
    const float* __restrict__ x, u16* __restrict__ xT)
{
  const int p0 = blockIdx.x * 64, c0 = blockIdx.y * 64, b = blockIdx.z;
  __shared__ float tile[64*65];
  const int t = threadIdx.x;
  {
    const int cc = t >> 2, ps = (t & 3) * 16;
    const float* src = x + ((size_t)b*C_ + c0 + cc)*HW_ + p0 + ps;
    float4 f0 = *(const float4*)(src);
    float4 f1 = *(const float4*)(src + 4);
    float4 f2 = *(const float4*)(src + 8);
    float4 f3 = *(const float4*)(src + 12);
    float* d = tile + cc*65 + ps;
    d[0]=f0.x; d[1]=f0.y; d[2]=f0.z;  d[3]=f0.w;
    d[4]=f1.x; d[5]=f1.y; d[6]=f1.z;  d[7]=f1.w;
    d[8]=f2.x; d[9]=f2.y; d[10]=f2.z; d[11]=f2.w;
    d[12]=f3.x; d[13]=f3.y; d[14]=f3.z; d[15]=f3.w;
  }
  __syncthreads();
#pragma unroll
  for (int pass = 0; pass < 2; ++pass) {
    const int pr = pass*32 + (t >> 3), cs = (t & 7) * 8;
    union { u16 s[8]; uint4 v; } tmp;
#pragma unroll
    for (int i = 0; i < 8; ++i) tmp.s[i] = f2bf(tile[(cs + i)*65 + pr]);
    *(uint4*)(xT + ((size_t)b*HW_ + p0 + pr)*C_ + c0 + cs) = tmp.v;
  }
}

// ---------------- prepass: weights fp32 -> bf16 parked in d_out (dead until outW).
__global__ __launch_bounds__(256) void wconv_kernel(
    const float* __restrict__ Wq, const float* __restrict__ Wk,
    const float* __restrict__ Wv, u16* __restrict__ wdst)
{
  const int i = (blockIdx.x * 256 + threadIdx.x) * 4;
  const float* src; int off;
  if (i < 32768)      { src = Wq; off = 0; }
  else if (i < 65536) { src = Wk; off = 32768; }
  else                { src = Wv; off = 65536; }
  float4 f = *(const float4*)(src + (i - off));
  union { u16 s[4]; uint2 v; } o;
  o.s[0] = f2bf(f.x); o.s[1] = f2bf(f.y); o.s[2] = f2bf(f.z); o.s[3] = f2bf(f.w);
  *(uint2*)(wdst + i) = o.v;
}

// ---------------- fused MFMA projection GEMM (q,k,v in one launch):
// grid (72, 5, 8). y=0 -> qk[b][pix][128]; y=1..4 -> vp[b][pix][512] tile (y-1)*128.
__global__ __launch_bounds__(256) void mfma_proj(
    const u16* __restrict__ xT, const u16* __restrict__ Wt,
    const float* __restrict__ bq, const float* __restrict__ bk,
    const float* __restrict__ bv, u16* __restrict__ qkp, u16* __restrict__ vpp)
{
  __shared__ __align__(16) u16 As[2*128*32];   // double-buffered [pix][32k]
  __shared__ __align__(16) u16 Bs[2*128*32];   // double-buffered [ch][32k]
  const int b  = blockIdx.z;
  const int p0 = blockIdx.x * 128;
  const int n0 = blockIdx.y * 128;           // global weight row base (0..512)
  const int t = threadIdx.x;
  const int wv = t >> 6, lane = t & 63;
  const int wr = wv >> 1, wc = wv & 1;       // wave's 64x64 quadrant
  const int lhi = lane >> 4, llo = lane & 15;

  // staging: lane covers row = chunk*16 + (lane>>2), k-quad = (lane&3)^(row&3)
  const int srow = lane >> 2;
  const int skq  = (lane & 3) ^ (srow & 3);
  const u16* aG = xT + ((size_t)b*HW_ + p0 + srow) * C_ + skq * 8;
  const u16* bG = Wt + ((size_t)(n0 + srow)) * C_ + skq * 8;

  // frag read offsets (elems): quad q of row R sits at position q^(R&3)
  const int swz = (lhi ^ (llo & 3)) * 8;
  int aOff[4], bOff[4];
#pragma unroll
  for (int i = 0; i < 4; ++i) aOff[i] = (wr*64 + i*16 + llo)*32 + swz;
#pragma unroll
  for (int j = 0; j < 4; ++j) bOff[j] = (wc*64 + j*16 + llo)*32 + swz;

  auto stage = [&](int bi, int k0) {
#pragma unroll
    for (int i = 0; i < 2; ++i) {
      const int chunk = wv*2 + i;            // wave-uniform
      gld16(aG + (size_t)chunk*16*C_ + k0, (void*)(As + bi*4096 + chunk*512));
      gld16(bG + (size_t)chunk*16*C_ + k0, (void*)(Bs + bi*4096 + chunk*512));
    }
  };

  f32x4 acc[4][4];
#pragma unroll
  for (int i = 0; i < 4; ++i)
#pragma unroll
    for (int j = 0; j < 4; ++j) acc[i][j] = (f32x4){0.f, 0.f, 0.f, 0.f};

  stage(0, 0);
  for (int ki = 0; ki < 16; ++ki) {
    const int cur = ki & 1;
    asm volatile("s_waitcnt vmcnt(0)" ::: "memory");
    __builtin_amdgcn_s_barrier();
    asm volatile("" ::: "memory");
    if (ki < 15) stage(cur ^ 1, (ki + 1) * 32);   // in flight across compute
    const u16* Ab = As + cur*4096;
    const u16* Bb = Bs + cur*4096;
    short8 af[4], bfr[4];
#pragma unroll
    for (int i = 0; i < 4; ++i) af[i]  = *(const short8*)(Ab + aOff[i]);
#pragma unroll
    for (int j = 0; j < 4; ++j) bfr[j] = *(const short8*)(Bb + bOff[j]);
#pragma unroll
    for (int i = 0; i < 4; ++i)
#pragma unroll
      for (int j = 0; j < 4; ++j)
        acc[i][j] = __builtin_amdgcn_mfma_f32_16x16x32_bf16(af[i], bfr[j], acc[i][j], 0, 0, 0);
  }

  // epilogue: D row (pix) = quad*4+reg, col = lane&15; route by blockIdx.y
  const bool isQK = (blockIdx.y == 0);
  u16* op = isQK ? qkp : vpp;
  const int NCH = isQK ? 128 : 512;
  const int chBase = isQK ? 0 : (n0 - 128);
#pragma unroll
  for (int j = 0; j < 4; ++j) {
    const int chl = wc*64 + j*16 + llo;      // 0..127 within tile
    const float bias = isQK ? ((chl < 64) ? bq[chl] : bk[chl - 64])
                            : bv[chBase + chl];
#pragma unroll
    for (int i = 0; i < 4; ++i) {
      const int pr = p0 + wr*64 + i*16 + lhi*4;
      u16* dst = op + ((size_t)b*HW_ + pr) * NCH + chBase + chl;
#pragma unroll
      for (int r = 0; r < 4; ++r)
        dst[(size_t)r * NCH] = f2bf(acc[i][j][r] + bias);
    }
  }
}

// ---------------- eH logits: block per (w, b). qk bf16 [pix][128]: q=ch 0..63, k=ch 64..127
// writes raw fp32 logits attL[b][h][w][96] (diag = -inf)
__global__ __launch_bounds__(256) void score_col_kernel(
    const u16* __restrict__ qk, float* __restrict__ attL)
{
  const int w = blockIdx.x, b = blockIdx.y;
  __shared__ float qs[96*68];
  __shared__ float ks[96*68];
  const int t = threadIdx.x;
  for (int r = 0; r < 6; ++r) {
    int f = r*256 + t;                   // 1536 uint4 chunks
    int p = f >> 4, c8 = (f & 15) * 8;
    uint4 u = *(const uint4*)(qk + ((size_t)(b*HW_ + p*W_ + w))*128 + c8);
    float d[8];
    d[0]=bf2f(u.x & 0xffff); d[1]=bf2f(u.x >> 16);
    d[2]=bf2f(u.y & 0xffff); d[3]=bf2f(u.y >> 16);
    d[4]=bf2f(u.z & 0xffff); d[5]=bf2f(u.z >> 16);
    d[6]=bf2f(u.w & 0xffff); d[7]=bf2f(u.w >> 16);
    float* dst = (c8 < 64) ? (qs + p*68 + c8) : (ks + p*68 + (c8 - 64));
    *(float4*)(dst)     = make_float4(d[0], d[1], d[2], d[3]);
    *(float4*)(dst + 4) = make_float4(d[4], d[5], d[6], d[7]);
  }
  __syncthreads();
  const int ty = t >> 4, tx = t & 15;
  float e[6][6] = {};
#pragma unroll 8
  for (int c = 0; c < 64; ++c) {
    float qv[6], kv[6];
#pragma unroll
    for (int a = 0; a < 6; ++a) qv[a] = qs[(ty*6+a)*68 + c];
#pragma unroll
    for (int bb = 0; bb < 6; ++bb) kv[bb] = ks[(tx*6+bb)*68 + c];
#pragma unroll
    for (int a = 0; a < 6; ++a)
#pragma unroll
      for (int bb = 0; bb < 6; ++bb)
        e[a][bb] = fmaf(qv[a], kv[bb], e[a][bb]);
  }
#pragma unroll
  for (int a = 0; a < 6; ++a) {
    int h = ty*6 + a;
    size_t base = ((size_t)((b*H_ + h)*W_ + w)) * 96;
#pragma unroll
    for (int bb = 0; bb < 6; ++bb) {
      int p = tx*6 + bb;
      attL[base + p] = (h == p) ? -INFINITY : e[a][bb];
    }
  }
}

// ---------------- eW logits + fused softmax: block per (h, b).
__global__ __launch_bounds__(256) void score_row_kernel(
    const u16* __restrict__ qk, const float* __restrict__ attL,
    u16* __restrict__ attF)
{
  const int h = blockIdx.x, b = blockIdx.y;
  __shared__ float smem[2*96*68];            // qs|ks; reused as esW[96][97]
  float* qs = smem;
  float* ks = smem + 96*68;
  const int t = threadIdx.x;
  for (int r = 0; r < 6; ++r) {
    int f = r*256 + t;
    int p = f >> 4, c8 = (f & 15) * 8;
    uint4 u = *(const uint4*)(qk + ((size_t)(b*HW_ + h*W_ + p))*128 + c8);
    float d[8];
    d[0]=bf2f(u.x & 0xffff); d[1]=bf2f(u.x >> 16);
    d[2]=bf2f(u.y & 0xffff); d[3]=bf2f(u.y >> 16);
    d[4]=bf2f(u.z & 0xffff); d[5]=bf2f(u.z >> 16);
    d[6]=bf2f(u.w & 0xffff); d[7]=bf2f(u.w >> 16);
    float* dst = (c8 < 64) ? (qs + p*68 + c8) : (ks + p*68 + (c8 - 64));
    *(float4*)(dst)     = make_float4(d[0], d[1], d[2], d[3]);
    *(float4*)(dst + 4) = make_float4(d[4], d[5], d[6], d[7]);
  }
  __syncthreads();
  const int ty = t >> 4, tx = t & 15;
  float e[6][6] = {};
#pragma unroll 8
  for (int c = 0; c < 64; ++c) {
    float qv[6], kv[6];
#pragma unroll
    for (int a = 0; a < 6; ++a) qv[a] = qs[(ty*6+a)*68 + c];
#pragma unroll
    for (int bb = 0; bb < 6; ++bb) kv[bb] = ks[(tx*6+bb)*68 + c];
#pragma unroll
    for (int a = 0; a < 6; ++a)
#pragma unroll
      for (int bb = 0; bb < 6; ++bb)
        e[a][bb] = fmaf(qv[a], kv[bb], e[a][bb]);
  }
  __syncthreads();                           // all qs/ks reads done
  float* esW = smem;                         // [96][97]
#pragma unroll
  for (int a = 0; a < 6; ++a)
#pragma unroll
    for (int bb = 0; bb < 6; ++bb)
      esW[(ty*6 + a)*97 + tx*6 + bb] = e[a][bb];
  __syncthreads();
  // fused softmax: 2 lanes per pixel (lane pair via shfl_xor 1)
  if (t < 192) {
    const int w = t >> 1, hf = t & 1;
    float v[96];
    if (hf == 0) {
      const float4* src = (const float4*)(attL + ((size_t)((b*H_ + h)*W_ + w)) * 96);
#pragma unroll
      for (int i = 0; i < 24; ++i) {
        float4 f4 = src[i];
        v[4*i]=f4.x; v[4*i+1]=f4.y; v[4*i+2]=f4.z; v[4*i+3]=f4.w;
      }
    } else {
      const float* src = esW + w*97;
#pragma unroll
      for (int i = 0; i < 96; ++i) v[i] = src[i];
    }
    float m = v[0];
#pragma unroll
    for (int i = 1; i < 96; ++i) m = fmaxf(m, v[i]);
    m = fmaxf(m, __shfl_xor(m, 1, 64));
    float s = 0.f;
#pragma unroll
    for (int i = 0; i < 96; ++i) { v[i] = __expf(v[i] - m); s += v[i]; }
    s += __shfl_xor(s, 1, 64);
    const float inv = __frcp_rn(s);
    u16* dst = attF + ((size_t)((b*H_ + h)*W_ + w)) * 192 + hf*96;
#pragma unroll
    for (int i = 0; i < 12; ++i) {
      union { u16 s4[8]; uint4 u; } o;
#pragma unroll
      for (int k = 0; k < 8; ++k) o.s4[k] = f2bf(v[i*8 + k] * inv);
      ((uint4*)dst)[i] = o.u;
    }
  }
}

// ---------------- outH (MFMA): block per (w, slot, b).
// tmpo[slot][b][w][h][cl] = sum_p attH[h,p] * v[p][cl]
// A = attH [h][p] row-major LDS; B = vT [c][p] (transpose-staged, XOR-swz);
// D[h][c] packed bf16 via LDS, coalesced uint4 store.
__global__ __launch_bounds__(256) void outH_kernel(
    const u16* __restrict__ attF, const u16* __restrict__ vp,
    int cr0, u16* __restrict__ tmpo)
{
  const int w = blockIdx.x, b = blockIdx.z;
  const int c0 = cr0 + (int)blockIdx.y * 128;
  u16* tdst = tmpo + (size_t)blockIdx.y * TMPO_ELEMS;
  __shared__ __align__(16) u16 aLds[96*104];    // attH [h][p]
  __shared__ __align__(16) u16 vLds[128*104];   // vT [c][p^swz]; reused as outLds[96][136]
  const int t = threadIdx.x;
  // stage attH: 1152 uint4 (96 h x 12 p-groups)
  for (int i = 0; i < 5; ++i) {
    int f = i*256 + t;
    if (f < 1152) {
      int hh = f / 12, pg = f % 12;
      *(uint4*)(aLds + hh*104 + pg*8) =
          *(const uint4*)(attF + ((size_t)((b*H_ + hh)*W_ + w))*192 + pg*8);
    }
  }
  // stage vT: 96 p x 16 cg, transpose via 8 u16 writes, XOR-8block swizzle on p
  {
    const int pb = t >> 4, cg = t & 15;
    const int sw = (cg & 3) << 3;
    const u16* src = vp + ((size_t)b*HW_ + (size_t)pb*W_ + w)*C_ + c0 + cg*8;
    u16* dstc = vLds + (cg*8)*104;
#pragma unroll
    for (int i = 0; i < 6; ++i) {
      uint4 u = *(const uint4*)(src + (size_t)(i*16)*W_*C_);
      u16* d = dstc + ((pb + i*16) ^ sw);
      d[0*104]=(u16)u.x; d[1*104]=(u16)(u.x>>16);
      d[2*104]=(u16)u.y; d[3*104]=(u16)(u.y>>16);
      d[4*104]=(u16)u.z; d[5*104]=(u16)(u.z>>16);
      d[6*104]=(u16)u.w; d[7*104]=(u16)(u.w>>16);
    }
  }
  __syncthreads();
  const int wv = t >> 6, lane = t & 63;
  const int wm = wv >> 1, wn = wv & 1;        // wave: M 48 (3 tiles) x N 64 (4 tiles)
  const int lhi = lane >> 4, llo = lane & 15;
  f32x4 acc[3][4];
#pragma unroll
  for (int mi = 0; mi < 3; ++mi)
#pragma unroll
    for (int ni = 0; ni < 4; ++ni) acc[mi][ni] = (f32x4){0.f,0.f,0.f,0.f};
#pragma unroll
  for (int ks = 0; ks < 3; ++ks) {
    const int k0 = ks*32;
    short8 af[3], bfv[4];
#pragma unroll
    for (int mi = 0; mi < 3; ++mi)
      af[mi] = *(const short8*)(aLds + (wm*48 + mi*16 + llo)*104 + k0 + lhi*8);
#pragma unroll
    for (int ni = 0; ni < 4; ++ni) {
      int c = wn*64 + ni*16 + llo;
      bfv[ni] = *(const short8*)(vLds + c*104 + ((k0 + lhi*8) ^ (((c>>3)&3)<<3)));
    }
#pragma unroll
    for (int mi = 0; mi < 3; ++mi)
#pragma unroll
      for (int ni = 0; ni < 4; ++ni)
        acc[mi][ni] = __builtin_amdgcn_mfma_f32_16x16x32_bf16(af[mi], bfv[ni], acc[mi][ni], 0, 0, 0);
  }
  __syncthreads();                    // all vLds frag reads complete
  u16* outLds = vLds;                 // [96][136] bf16
#pragma unroll
  for (int mi = 0; mi < 3; ++mi)
#pragma unroll
    for (int ni = 0; ni < 4; ++ni)
#pragma unroll
      for (int r = 0; r < 4; ++r)
        outLds[(wm*48 + mi*16 + lhi*4 + r)*136 + wn*64 + ni*16 + llo] = f2bf(acc[mi][ni][r]);
  __syncthreads();
#pragma unroll
  for (int i = 0; i < 6; ++i) {       // 1536 uint4, coalesced
    int f = i*256 + t;
    int hh = f >> 4, cg = f & 15;
    *(uint4*)(tdst + (((size_t)b*W_ + w)*H_ + hh)*128 + cg*8) =
        *(const uint4*)(outLds + hh*136 + cg*8);
  }
}

// ---------------- outW (MFMA) + fuse outH tile + residual: block per (h, slot, b).
// out = gamma*(sum_p attW[w,p]*v[p][c] + tmpo) + x
// A = vT [c][p] (rows c -> D rows); B = attW [w][p] (rows w -> D cols).
__global__ __launch_bounds__(256) void outW_kernel(
    const u16* __restrict__ attF, const u16* __restrict__ vp,
    const u16* __restrict__ tmpo, const float* __restrict__ x,
    const float* __restrict__ gammap, int cr0, float* __restrict__ out)
{
  const int h = blockIdx.x, b = blockIdx.z;
  const int c0 = cr0 + (int)blockIdx.y * 128;
  const u16* tsrc = tmpo + (size_t)blockIdx.y * TMPO_ELEMS;
  __shared__ __align__(16) u16 aLds[96*104];    // attW [w][p]
  __shared__ __align__(16) u16 vLds[128*104];   // vT [c][p^swz]; reused as tmpoLds[96][136]
  const int t = threadIdx.x;
  // stage attW
  for (int i = 0; i < 5; ++i) {
    int f = i*256 + t;
    if (f < 1152) {
      int wl = f / 12, pg = f % 12;
      *(uint4*)(aLds + wl*104 + pg*8) =
          *(const uint4*)(attF + ((size_t)((b*H_ + h)*W_ + wl))*192 + 96 + pg*8);
    }
  }
  // stage vT (pixels h*W+p are contiguous rows)
  {
    const int pb = t >> 4, cg = t & 15;
    const int sw = (cg & 3) << 3;
    const u16* src = vp + ((size_t)b*HW_ + (size_t)h*W_ + pb)*C_ + c0 + cg*8;
    u16* dstc = vLds + (cg*8)*104;
#pragma unroll
    for (int i = 0; i < 6; ++i) {
      uint4 u = *(const uint4*)(src + (size_t)(i*16)*C_);
      u16* d = dstc + ((pb + i*16) ^ sw);
      d[0*104]=(u16)u.x; d[1*104]=(u16)(u.x>>16);
      d[2*104]=(u16)u.y; d[3*104]=(u16)(u.y>>16);
      d[4*104]=(u16)u.z; d[5*104]=(u16)(u.z>>16);
      d[6*104]=(u16)u.w; d[7*104]=(u16)(u.w>>16);
    }
  }
  __syncthreads();
  const int wv = t >> 6, lane = t & 63;
  const int wm = wv >> 1, wn = wv & 1;        // wave: M 64 c (4 tiles) x N 48 w (3 tiles)
  const int lhi = lane >> 4, llo = lane & 15;
  f32x4 acc[4][3];
#pragma unroll
  for (int mi = 0; mi < 4; ++mi)
#pragma unroll
    for (int ni = 0; ni < 3; ++ni) acc[mi][ni] = (f32x4){0.f,0.f,0.f,0.f};
#pragma unroll
  for (int ks = 0; ks < 3; ++ks) {
    const int k0 = ks*32;
    short8 af[4], bfa[3];
#pragma unroll
    for (int mi = 0; mi < 4; ++mi) {
      int c = wm*64 + mi*16 + llo;
      af[mi] = *(const short8*)(vLds + c*104 + ((k0 + lhi*8) ^ (((c>>3)&3)<<3)));
    }
#pragma unroll
    for (int ni = 0; ni < 3; ++ni)
      bfa[ni] = *(const short8*)(aLds + (wn*48 + ni*16 + llo)*104 + k0 + lhi*8);
#pragma unroll
    for (int mi = 0; mi < 4; ++mi)
#pragma unroll
      for (int ni = 0; ni < 3; ++ni)
        acc[mi][ni] = __builtin_amdgcn_mfma_f32_16x16x32_bf16(af[mi], bfa[ni], acc[mi][ni], 0, 0, 0);
  }
  __syncthreads();                    // vLds frag reads complete
  u16* tmpoLds = vLds;                // [96 w][136]
#pragma unroll
  for (int i = 0; i < 6; ++i) {       // coalesced restage of tmpo tile
    int f = i*256 + t;
    int wl = f >> 4, cg = f & 15;
    *(uint4*)(tmpoLds + wl*136 + cg*8) =
        *(const uint4*)(tsrc + (((size_t)b*W_ + wl)*H_ + h)*128 + cg*8);
  }
  __syncthreads();
  const float g = gammap[0];
#pragma unroll
  for (int mi = 0; mi < 4; ++mi) {
#pragma unroll
    for (int r = 0; r < 4; ++r) {
      const int cl = wm*64 + mi*16 + lhi*4 + r;
      const size_t rowb = ((size_t)(b*C_ + c0 + cl)*H_ + h)*W_;
#pragma unroll
      for (int ni = 0; ni < 3; ++ni) {
        const int wcol = wn*48 + ni*16 + llo;
        out[rowb + wcol] = g*(acc[mi][ni][r] + bf2f(tmpoLds[wcol*136 + cl])) + x[rowb + wcol];
      }
    }
  }
}

extern "C" void kernel_launch(void* const* d_in, const int* in_sizes, int n_in,
                              void* d_out, int out_size, void* d_ws, size_t ws_size,
                              hipStream_t stream) {
  const float* x     = (const float*)d_in[0];
  const float* Wq    = (const float*)d_in[1];
  const float* bq    = (const float*)d_in[2];
  const float* Wk    = (const float*)d_in[3];
  const float* bk    = (const float*)d_in[4];
  const float* Wv    = (const float*)d_in[5];
  const float* bv    = (const float*)d_in[6];
  const float* gamma = (const float*)d_in[7];
  float* out = (float*)d_out;
  char* ws = (char*)d_ws;

  // ws layout (169,869,312 B):
  //   xT    @0        : bf16 [B][HW][512] (75,497,472 B), live through mfma_proj
  //   attF  @0        : bf16 [B][H][W][192] (28,311,552 B)  — overlays dead xT
  //   attL  @28311552 : fp32 [B][H][W][96]  (28,311,552 B)  — overlays dead xT
  //   tmpo  @56623104 : bf16 2 slots x [B][W][H][128] (2 x 18,874,368 B)
  //   qk    @75497472 : bf16 [B][HW][128] (18,874,368 B)
  //   vp    @94371840 : bf16 [B][HW][512] (75,497,472 B)
  // weights: bf16 [640][512] (655,360 B) parked in d_out (dead until outW).
  u16*   xT   = (u16*)ws;
  u16*   attF = (u16*)ws;
  float* attL = (float*)(ws + 28311552);
  u16*   tmpo = (u16*)(ws + 56623104);
  u16*   qk   = (u16*)(ws + 75497472);
  u16*   vp   = (u16*)(ws + 94371840);
  u16*   wbf  = (u16*)d_out;

  dim3 blk(256);
  wconv_kernel<<<320, blk, 0, stream>>>(Wq, Wk, Wv, wbf);
  transpose_kernel<<<dim3(HW_/64, C_/64, B_), blk, 0, stream>>>(x, xT);
  mfma_proj<<<dim3(HW_/128, 5, B_), blk, 0, stream>>>(xT, wbf, bq, bk, bv, qk, vp);
  score_col_kernel<<<dim3(W_, B_), blk, 0, stream>>>(qk, attL);
  score_row_kernel<<<dim3(H_, B_), blk, 0, stream>>>(qk, attL, attF);
  for (int r = 0; r < 2; ++r) {
    outH_kernel<<<dim3(W_, 2, B_), blk, 0, stream>>>(attF, vp, r*256, tmpo);
    outW_kernel<<<dim3(H_, 2, B_), blk, 0, stream>>>(attF, vp, tmpo, x, gamma, r*256, out);
  }
}